// Round 10
// baseline (807.767 us; speedup 1.0000x reference)
//
#include <hip/hip_runtime.h>
#include <hip/hip_bf16.h>
#include <math.h>

#define D_MODEL 256
#define D_INNER 512
#define D_STATE 16
#define D_CONV 4
#define DT_RANK 16
#define N_LAYERS 4
#define CITY 300
#define BATCH 32
#define SEQ 300
#define NTOK (BATCH * SEQ)   // 9600
#define NSEG 12
#define SEGLEN (SEQ / NSEG)  // 25

typedef __attribute__((ext_vector_type(8))) short short8v;
typedef __attribute__((ext_vector_type(4))) float f32x4;

__device__ __forceinline__ float fast_sig(float x) {
    return __builtin_amdgcn_rcpf(1.f + __expf(-x));
}

__device__ __forceinline__ unsigned int pack_bf16(float a, float b) {
    __hip_bfloat16 ha = __float2bfloat16(a);
    __hip_bfloat16 hb = __float2bfloat16(b);
    unsigned short ua = *reinterpret_cast<unsigned short*>(&ha);
    unsigned short ub = *reinterpret_cast<unsigned short*>(&hb);
    return (unsigned int)ua | ((unsigned int)ub << 16);
}

// ---------------- embedding ----------------
__global__ void embed_kernel(const float* __restrict__ coords,
                             const float* __restrict__ eW,
                             const float* __restrict__ eb,
                             float* __restrict__ x) {
    int t = blockIdx.x, d = threadIdx.x;
    float c0 = coords[t * 2 + 0];
    float c1 = coords[t * 2 + 1];
    x[t * D_MODEL + d] = c0 * eW[d * 2 + 0] + c1 * eW[d * 2 + 1] + eb[d];
}

// ------------- residual add + layernorm -------------
__global__ void ln_res_kernel(const float* __restrict__ xin, float* __restrict__ resid,
                              float* __restrict__ h,
                              const float* __restrict__ w,
                              const float* __restrict__ b, int first) {
    int t = blockIdx.x, d = threadIdx.x;
    float r = xin[t * D_MODEL + d] + (first ? 0.f : resid[t * D_MODEL + d]);
    resid[t * D_MODEL + d] = r;
    float s1 = r, s2 = r * r;
#pragma unroll
    for (int m = 1; m < 64; m <<= 1) {
        s1 += __shfl_xor(s1, m);
        s2 += __shfl_xor(s2, m);
    }
    __shared__ float p1[4], p2[4];
    if ((d & 63) == 0) { p1[d >> 6] = s1; p2[d >> 6] = s2; }
    __syncthreads();
    s1 = (p1[0] + p1[1]) + (p1[2] + p1[3]);
    s2 = (p2[0] + p2[1]) + (p2[2] + p2[3]);
    float mean = s1 * (1.f / D_MODEL);
    float var = s2 * (1.f / D_MODEL) - mean * mean;
    h[t * D_MODEL + d] = (r - mean) * rsqrtf(var + 1e-5f) * w[d] + b[d];
}

// ------------- final add + RMSNorm -------------
__global__ void final_rms_kernel(const float* __restrict__ xin, const float* __restrict__ resid,
                                 const float* __restrict__ w,
                                 const float* __restrict__ b, float* __restrict__ h) {
    int t = blockIdx.x, d = threadIdx.x;
    float r = xin[t * D_MODEL + d] + resid[t * D_MODEL + d];
    float s2 = r * r;
#pragma unroll
    for (int m = 1; m < 64; m <<= 1) s2 += __shfl_xor(s2, m);
    __shared__ float p2[4];
    if ((d & 63) == 0) p2[d >> 6] = s2;
    __syncthreads();
    s2 = (p2[0] + p2[1]) + (p2[2] + p2[3]);
    float rms = r * rsqrtf(s2 * (1.f / D_MODEL) + 1e-5f);
    h[t * D_MODEL + d] = rms * w[d] + b[d];
}

// ------------- bf16 MFMA GEMM: C[t,n] = sum_k A[t,k] * W[n,k] -------------
template <int BM, int BN, bool GN>
__global__ __launch_bounds__(256, 2) void gemm_mfma(const float* __restrict__ A,
                                                    const float* __restrict__ W,
                                                    float* __restrict__ C, int N, int K) {
    constexpr int TI = BM / 32;
    constexpr int TJ = BN / 32;
    __shared__ short Als[BM * 32];
    __shared__ short Bls[BN * 32];
    const int tid = threadIdx.x;
    const int lane = tid & 63, wid = tid >> 6;
    const int wr = wid >> 1, wc = wid & 1;
    const int t0 = blockIdx.x * BM, n0 = blockIdx.y * BN;
    f32x4 acc[TI][TJ] = {};

    for (int k0 = 0; k0 < K; k0 += 32) {
#pragma unroll
        for (int it = 0; it < BM / 64; ++it) {
            int s = tid + it * 256;
            int m = s >> 2, q = s & 3;
            const float* src = A + (size_t)(t0 + m) * K + k0 + q * 8;
            float4 v0 = *(const float4*)src;
            float4 v1 = *(const float4*)(src + 4);
            uint4 p;
            p.x = pack_bf16(v0.x, v0.y);
            p.y = pack_bf16(v0.z, v0.w);
            p.z = pack_bf16(v1.x, v1.y);
            p.w = pack_bf16(v1.z, v1.w);
            *(uint4*)&Als[(((m >> 4) * 4 + q) * 16 + (m & 15)) * 8] = p;
        }
#pragma unroll
        for (int it = 0; it < BN / 64; ++it) {
            int s = tid + it * 256;
            int n = s >> 2, q = s & 3;
            int nrow = n0 + n;
            float4 v0 = make_float4(0.f, 0.f, 0.f, 0.f), v1 = v0;
            if (!GN || nrow < N) {
                const float* src = W + (size_t)nrow * K + k0 + q * 8;
                v0 = *(const float4*)src;
                v1 = *(const float4*)(src + 4);
            }
            uint4 p;
            p.x = pack_bf16(v0.x, v0.y);
            p.y = pack_bf16(v0.z, v0.w);
            p.z = pack_bf16(v1.x, v1.y);
            p.w = pack_bf16(v1.z, v1.w);
            *(uint4*)&Bls[(((n >> 4) * 4 + q) * 16 + (n & 15)) * 8] = p;
        }
        __syncthreads();
        short8v af[TI], bf[TJ];
#pragma unroll
        for (int i = 0; i < TI; i++)
            af[i] = *(const short8v*)&Als[(wr * TI + i) * 512 + lane * 8];
#pragma unroll
        for (int j = 0; j < TJ; j++)
            bf[j] = *(const short8v*)&Bls[(wc * TJ + j) * 512 + lane * 8];
#pragma unroll
        for (int i = 0; i < TI; i++)
#pragma unroll
            for (int j = 0; j < TJ; j++)
                acc[i][j] = __builtin_amdgcn_mfma_f32_16x16x32_bf16(
                    af[i], bf[j], acc[i][j], 0, 0, 0);
        __syncthreads();
    }
    const int rq = lane >> 4, cn = lane & 15;
#pragma unroll
    for (int i = 0; i < TI; i++) {
        int trow = t0 + wr * (BM / 2) + i * 16 + rq * 4;
#pragma unroll
        for (int j = 0; j < TJ; j++) {
            int ncol = n0 + wc * (BN / 2) + j * 16 + cn;
            if (!GN || ncol < N) {
#pragma unroll
                for (int reg = 0; reg < 4; reg++)
                    C[(size_t)(trow + reg) * N + ncol] = acc[i][j][reg];
            }
        }
    }
}

// ------------- causal depthwise conv (k=4) + bias + SiLU, float4 -------------
__global__ void conv_silu_kernel(const float* __restrict__ xz,
                                 const float* __restrict__ cW,
                                 const float* __restrict__ cb,
                                 float* __restrict__ xc) {
    int idx = blockIdx.x * blockDim.x + threadIdx.x;  // 4-channel groups
    int d4 = (idx & 127) * 4;
    int t = idx >> 7;
    int l = t % SEQ;
    float4 acc = *(const float4*)(cb + d4);
    float4 wA = *(const float4*)(cW + (d4 + 0) * 4);
    float4 wB = *(const float4*)(cW + (d4 + 1) * 4);
    float4 wC = *(const float4*)(cW + (d4 + 2) * 4);
    float4 wD = *(const float4*)(cW + (d4 + 3) * 4);
#pragma unroll
    for (int k = 0; k < D_CONV; k++) {
        int ll = l - 3 + k;
        if (ll >= 0) {
            float4 v = *(const float4*)(xz + (size_t)(t - 3 + k) * 1024 + d4);
            float wa = (k == 0) ? wA.x : (k == 1) ? wA.y : (k == 2) ? wA.z : wA.w;
            float wb = (k == 0) ? wB.x : (k == 1) ? wB.y : (k == 2) ? wB.z : wB.w;
            float wc = (k == 0) ? wC.x : (k == 1) ? wC.y : (k == 2) ? wC.z : wC.w;
            float wd = (k == 0) ? wD.x : (k == 1) ? wD.y : (k == 2) ? wD.z : wD.w;
            acc.x = fmaf(v.x, wa, acc.x);
            acc.y = fmaf(v.y, wb, acc.y);
            acc.z = fmaf(v.z, wc, acc.z);
            acc.w = fmaf(v.w, wd, acc.w);
        }
    }
    float4 o;
    o.x = acc.x * fast_sig(acc.x);
    o.y = acc.y * fast_sig(acc.y);
    o.z = acc.z * fast_sig(acc.z);
    o.w = acc.w * fast_sig(acc.w);
    *(float4*)(xc + (size_t)t * 512 + d4) = o;
}

// ========== block-local 3-phase scan, 4 lanes per channel ==========
// grid (32, 32) = (channel-group of 16, b); block 768 thr = 12 waves = 12 segments.
// lane = g*16 + ch: thread owns states [g*4, g*4+4) of channel ch.
// Phase1: wave scans its segment from h=0 -> LDS h_end + sumdt.
// Phase2: 256 threads combine (s,ch) over 12 segments in LDS (entry -> initial state).
// Phase3: wave re-scans from initial state; g==0 lanes write gated output over xc.
__global__ __launch_bounds__(768) void scan_block(
    float* xcio, const float* __restrict__ dbl, const float* __restrict__ xz,
    const float* __restrict__ A_log, const float* __restrict__ Dskip,
    const float* __restrict__ dtW, const float* __restrict__ dtb) {
    __shared__ float lh[NSEG * D_STATE * 16];   // [seg][s][ch]
    __shared__ float lsd[NSEG * 16];            // [seg][ch]
    const int cg = blockIdx.x, b = blockIdx.y;
    const int tid = threadIdx.x;
    const int lane = tid & 63, seg = tid >> 6;
    const int ch = lane & 15, g = lane >> 4;
    const int d = (cg << 4) + ch;
    const int s0 = g << 2;
    const float LOG2E = 1.44269504088896340736f;
    float A4[4], dW4[4];
    {
        float4 av = *(const float4*)(A_log + (size_t)d * D_STATE + s0);
        A4[0] = -__expf(av.x) * LOG2E;
        A4[1] = -__expf(av.y) * LOG2E;
        A4[2] = -__expf(av.z) * LOG2E;
        A4[3] = -__expf(av.w) * LOG2E;
        float4 wv = *(const float4*)(dtW + (size_t)d * DT_RANK + s0);
        dW4[0] = wv.x; dW4[1] = wv.y; dW4[2] = wv.z; dW4[3] = wv.w;
    }
    const float dtbv = dtb[d], dsk = Dskip[d];
    const size_t tb = (size_t)b * SEQ + seg * SEGLEN;
    const float* __restrict__ dr = dbl + tb * 48;
    const float* xp = xcio + tb * 512 + d;
    const float* __restrict__ zp = xz + tb * 1024 + 512 + d;
    float* yp = xcio + tb * 512 + d;

    // ---------------- phase 1: local scan from h=0 ----------------
    {
        float h0 = 0.f, h1 = 0.f, h2 = 0.f, h3 = 0.f, sdt = 0.f;
        for (int l = 0; l < SEGLEN; l++) {
            const float* row = dr + (size_t)l * 48;
            float4 cdt = *(const float4*)(row + s0);
            float4 cB = *(const float4*)(row + 16 + s0);
            float xv = xp[(size_t)l * 512];
            float p = cdt.x * dW4[0];
            p = fmaf(cdt.y, dW4[1], p);
            p = fmaf(cdt.z, dW4[2], p);
            p = fmaf(cdt.w, dW4[3], p);
            p += __shfl_xor(p, 16);
            p += __shfl_xor(p, 32);
            float acc = p + dtbv;
            float dtt = fmaxf(acc, 0.f) + __logf(1.f + __expf(-fabsf(acc)));
            sdt += dtt;
            float dtx = dtt * xv;
            h0 = fmaf(exp2f(dtt * A4[0]), h0, dtx * cB.x);
            h1 = fmaf(exp2f(dtt * A4[1]), h1, dtx * cB.y);
            h2 = fmaf(exp2f(dtt * A4[2]), h2, dtx * cB.z);
            h3 = fmaf(exp2f(dtt * A4[3]), h3, dtx * cB.w);
        }
        lh[(seg * D_STATE + s0 + 0) * 16 + ch] = h0;
        lh[(seg * D_STATE + s0 + 1) * 16 + ch] = h1;
        lh[(seg * D_STATE + s0 + 2) * 16 + ch] = h2;
        lh[(seg * D_STATE + s0 + 3) * 16 + ch] = h3;
        if (g == 0) lsd[seg * 16 + ch] = sdt;
    }
    __syncthreads();
    // ---------------- phase 2: in-LDS prefix combine ----------------
    if (tid < D_STATE * 16) {
        int s = tid >> 4, c2 = tid & 15;
        float As2 = -__expf(A_log[(size_t)((cg << 4) + c2) * D_STATE + s]) * LOG2E;
        float H = 0.f;
        for (int sg = 0; sg < NSEG; sg++) {
            float hl = lh[(sg * D_STATE + s) * 16 + c2];
            float sd = lsd[sg * 16 + c2];
            lh[(sg * D_STATE + s) * 16 + c2] = H;
            H = fmaf(exp2f(As2 * sd), H, hl);
        }
    }
    __syncthreads();
    // ---------------- phase 3: re-scan from initial state ----------------
    {
        float h0 = lh[(seg * D_STATE + s0 + 0) * 16 + ch];
        float h1 = lh[(seg * D_STATE + s0 + 1) * 16 + ch];
        float h2 = lh[(seg * D_STATE + s0 + 2) * 16 + ch];
        float h3 = lh[(seg * D_STATE + s0 + 3) * 16 + ch];
        for (int l = 0; l < SEGLEN; l++) {
            const float* row = dr + (size_t)l * 48;
            float4 cdt = *(const float4*)(row + s0);
            float4 cB = *(const float4*)(row + 16 + s0);
            float4 cC = *(const float4*)(row + 32 + s0);
            float xv = xp[(size_t)l * 512];
            float zv = zp[(size_t)l * 1024];
            float p = cdt.x * dW4[0];
            p = fmaf(cdt.y, dW4[1], p);
            p = fmaf(cdt.z, dW4[2], p);
            p = fmaf(cdt.w, dW4[3], p);
            p += __shfl_xor(p, 16);
            p += __shfl_xor(p, 32);
            float acc = p + dtbv;
            float dtt = fmaxf(acc, 0.f) + __logf(1.f + __expf(-fabsf(acc)));
            float dtx = dtt * xv;
            h0 = fmaf(exp2f(dtt * A4[0]), h0, dtx * cB.x);
            h1 = fmaf(exp2f(dtt * A4[1]), h1, dtx * cB.y);
            h2 = fmaf(exp2f(dtt * A4[2]), h2, dtx * cB.z);
            h3 = fmaf(exp2f(dtt * A4[3]), h3, dtx * cB.w);
            float y = h0 * cC.x;
            y = fmaf(h1, cC.y, y);
            y = fmaf(h2, cC.z, y);
            y = fmaf(h3, cC.w, y);
            y += __shfl_xor(y, 16);
            y += __shfl_xor(y, 32);
            if (g == 0) {
                float gate = zv * fast_sig(zv);
                yp[(size_t)l * 512] = (y + xv * dsk) * gate;
            }
        }
    }
}

extern "C" void kernel_launch(void* const* d_in, const int* in_sizes, int n_in,
                              void* d_out, int out_size, void* d_ws, size_t ws_size,
                              hipStream_t stream) {
    const float* coords   = (const float*)d_in[0];
    const float* emb_W    = (const float*)d_in[1];
    const float* emb_b    = (const float*)d_in[2];
    const float* ln_w     = (const float*)d_in[3];
    const float* ln_b     = (const float*)d_in[4];
    const float* in_W     = (const float*)d_in[5];
    const float* conv_W   = (const float*)d_in[6];
    const float* conv_b   = (const float*)d_in[7];
    const float* xproj_W  = (const float*)d_in[8];
    const float* dtproj_W = (const float*)d_in[9];
    const float* dtproj_b = (const float*)d_in[10];
    const float* A_log    = (const float*)d_in[11];
    const float* D_skip   = (const float*)d_in[12];
    const float* out_W    = (const float*)d_in[13];
    const float* normf_w  = (const float*)d_in[14];
    const float* normf_b  = (const float*)d_in[15];
    const float* head_W   = (const float*)d_in[16];
    float* out = (float*)d_out;

    const int T = NTOK;  // 9600
    float* x     = (float*)d_ws;
    float* resid = x + (size_t)T * D_MODEL;
    float* h     = resid + (size_t)T * D_MODEL;
    float* xz    = h + (size_t)T * D_MODEL;
    float* xc    = xz + (size_t)T * 2 * D_INNER;   // conv output, then scan output (in place)
    float* dbl   = xc + (size_t)T * D_INNER;

    embed_kernel<<<T, D_MODEL, 0, stream>>>(coords, emb_W, emb_b, x);

    for (int i = 0; i < N_LAYERS; i++) {
        ln_res_kernel<<<T, D_MODEL, 0, stream>>>(x, resid, h, ln_w + i * D_MODEL,
                                                 ln_b + i * D_MODEL, i == 0);
        // in_proj: (9600,256) x (1024,256)^T -> (9600,1024)
        gemm_mfma<128, 128, false><<<dim3(T / 128, 8), 256, 0, stream>>>(
            h, in_W + (size_t)i * 2 * D_INNER * D_MODEL, xz, 2 * D_INNER, D_MODEL);
        conv_silu_kernel<<<T * 128 / 256, 256, 0, stream>>>(
            xz, conv_W + i * D_INNER * D_CONV, conv_b + i * D_INNER, xc);
        // xproj: (9600,512) x (48,512)^T -> (9600,48)
        gemm_mfma<64, 64, true><<<dim3(T / 64, 1), 256, 0, stream>>>(
            xc, xproj_W + (size_t)i * 48 * D_INNER, dbl, 48, D_INNER);
        // block-local 3-phase scan, 4 lanes/channel
        scan_block<<<dim3(32, BATCH), 768, 0, stream>>>(
            xc, dbl, xz, A_log + (size_t)i * D_INNER * D_STATE, D_skip + i * D_INNER,
            dtproj_W + (size_t)i * D_INNER * DT_RANK, dtproj_b + i * D_INNER);
        // out_proj: (9600,512) x (256,512)^T -> (9600,256)
        gemm_mfma<64, 64, false><<<dim3(T / 64, 4), 256, 0, stream>>>(
            xc, out_W + (size_t)i * D_MODEL * D_INNER, x, D_MODEL, D_INNER);
    }

    final_rms_kernel<<<T, D_MODEL, 0, stream>>>(x, resid, normf_w, normf_b, h);
    // head: (9600,256) x (300,256)^T -> (9600,300)
    gemm_mfma<64, 64, true><<<dim3(T / 64, 5), 256, 0, stream>>>(
        h, head_W, out, CITY, D_MODEL);
}

// Round 11
// 693.916 us; speedup vs baseline: 1.1641x; 1.1641x over previous
//
#include <hip/hip_runtime.h>
#include <hip/hip_bf16.h>
#include <math.h>

#define D_MODEL 256
#define D_INNER 512
#define D_STATE 16
#define D_CONV 4
#define DT_RANK 16
#define N_LAYERS 4
#define CITY 300
#define BATCH 32
#define SEQ 300
#define NTOK (BATCH * SEQ)   // 9600
#define NSEG 12
#define SEGLEN (SEQ / NSEG)  // 25

typedef __attribute__((ext_vector_type(8))) short short8v;
typedef __attribute__((ext_vector_type(4))) float f32x4;

__device__ __forceinline__ float fast_sig(float x) {
    return __builtin_amdgcn_rcpf(1.f + __expf(-x));
}

__device__ __forceinline__ unsigned int pack_bf16(float a, float b) {
    __hip_bfloat16 ha = __float2bfloat16(a);
    __hip_bfloat16 hb = __float2bfloat16(b);
    unsigned short ua = *reinterpret_cast<unsigned short*>(&ha);
    unsigned short ub = *reinterpret_cast<unsigned short*>(&hb);
    return (unsigned int)ua | ((unsigned int)ub << 16);
}

// ---------------- embedding ----------------
__global__ void embed_kernel(const float* __restrict__ coords,
                             const float* __restrict__ eW,
                             const float* __restrict__ eb,
                             float* __restrict__ x) {
    int t = blockIdx.x, d = threadIdx.x;
    float c0 = coords[t * 2 + 0];
    float c1 = coords[t * 2 + 1];
    x[t * D_MODEL + d] = c0 * eW[d * 2 + 0] + c1 * eW[d * 2 + 1] + eb[d];
}

// ------------- residual add + layernorm -------------
__global__ void ln_res_kernel(const float* __restrict__ xin, float* __restrict__ resid,
                              float* __restrict__ h,
                              const float* __restrict__ w,
                              const float* __restrict__ b, int first) {
    int t = blockIdx.x, d = threadIdx.x;
    float r = xin[t * D_MODEL + d] + (first ? 0.f : resid[t * D_MODEL + d]);
    resid[t * D_MODEL + d] = r;
    float s1 = r, s2 = r * r;
#pragma unroll
    for (int m = 1; m < 64; m <<= 1) {
        s1 += __shfl_xor(s1, m);
        s2 += __shfl_xor(s2, m);
    }
    __shared__ float p1[4], p2[4];
    if ((d & 63) == 0) { p1[d >> 6] = s1; p2[d >> 6] = s2; }
    __syncthreads();
    s1 = (p1[0] + p1[1]) + (p1[2] + p1[3]);
    s2 = (p2[0] + p2[1]) + (p2[2] + p2[3]);
    float mean = s1 * (1.f / D_MODEL);
    float var = s2 * (1.f / D_MODEL) - mean * mean;
    h[t * D_MODEL + d] = (r - mean) * rsqrtf(var + 1e-5f) * w[d] + b[d];
}

// ------------- final add + RMSNorm -------------
__global__ void final_rms_kernel(const float* __restrict__ xin, const float* __restrict__ resid,
                                 const float* __restrict__ w,
                                 const float* __restrict__ b, float* __restrict__ h) {
    int t = blockIdx.x, d = threadIdx.x;
    float r = xin[t * D_MODEL + d] + resid[t * D_MODEL + d];
    float s2 = r * r;
#pragma unroll
    for (int m = 1; m < 64; m <<= 1) s2 += __shfl_xor(s2, m);
    __shared__ float p2[4];
    if ((d & 63) == 0) p2[d >> 6] = s2;
    __syncthreads();
    s2 = (p2[0] + p2[1]) + (p2[2] + p2[3]);
    float rms = r * rsqrtf(s2 * (1.f / D_MODEL) + 1e-5f);
    h[t * D_MODEL + d] = rms * w[d] + b[d];
}

// ------------- bf16 MFMA GEMM: C[t,n] = sum_k A[t,k] * W[n,k] -------------
template <int BM, int BN, bool GN>
__global__ __launch_bounds__(256, 2) void gemm_mfma(const float* __restrict__ A,
                                                    const float* __restrict__ W,
                                                    float* __restrict__ C, int N, int K) {
    constexpr int TI = BM / 32;
    constexpr int TJ = BN / 32;
    __shared__ short Als[BM * 32];
    __shared__ short Bls[BN * 32];
    const int tid = threadIdx.x;
    const int lane = tid & 63, wid = tid >> 6;
    const int wr = wid >> 1, wc = wid & 1;
    const int t0 = blockIdx.x * BM, n0 = blockIdx.y * BN;
    f32x4 acc[TI][TJ] = {};

    for (int k0 = 0; k0 < K; k0 += 32) {
#pragma unroll
        for (int it = 0; it < BM / 64; ++it) {
            int s = tid + it * 256;
            int m = s >> 2, q = s & 3;
            const float* src = A + (size_t)(t0 + m) * K + k0 + q * 8;
            float4 v0 = *(const float4*)src;
            float4 v1 = *(const float4*)(src + 4);
            uint4 p;
            p.x = pack_bf16(v0.x, v0.y);
            p.y = pack_bf16(v0.z, v0.w);
            p.z = pack_bf16(v1.x, v1.y);
            p.w = pack_bf16(v1.z, v1.w);
            *(uint4*)&Als[(((m >> 4) * 4 + q) * 16 + (m & 15)) * 8] = p;
        }
#pragma unroll
        for (int it = 0; it < BN / 64; ++it) {
            int s = tid + it * 256;
            int n = s >> 2, q = s & 3;
            int nrow = n0 + n;
            float4 v0 = make_float4(0.f, 0.f, 0.f, 0.f), v1 = v0;
            if (!GN || nrow < N) {
                const float* src = W + (size_t)nrow * K + k0 + q * 8;
                v0 = *(const float4*)src;
                v1 = *(const float4*)(src + 4);
            }
            uint4 p;
            p.x = pack_bf16(v0.x, v0.y);
            p.y = pack_bf16(v0.z, v0.w);
            p.z = pack_bf16(v1.x, v1.y);
            p.w = pack_bf16(v1.z, v1.w);
            *(uint4*)&Bls[(((n >> 4) * 4 + q) * 16 + (n & 15)) * 8] = p;
        }
        __syncthreads();
        short8v af[TI], bf[TJ];
#pragma unroll
        for (int i = 0; i < TI; i++)
            af[i] = *(const short8v*)&Als[(wr * TI + i) * 512 + lane * 8];
#pragma unroll
        for (int j = 0; j < TJ; j++)
            bf[j] = *(const short8v*)&Bls[(wc * TJ + j) * 512 + lane * 8];
#pragma unroll
        for (int i = 0; i < TI; i++)
#pragma unroll
            for (int j = 0; j < TJ; j++)
                acc[i][j] = __builtin_amdgcn_mfma_f32_16x16x32_bf16(
                    af[i], bf[j], acc[i][j], 0, 0, 0);
        __syncthreads();
    }
    const int rq = lane >> 4, cn = lane & 15;
#pragma unroll
    for (int i = 0; i < TI; i++) {
        int trow = t0 + wr * (BM / 2) + i * 16 + rq * 4;
#pragma unroll
        for (int j = 0; j < TJ; j++) {
            int ncol = n0 + wc * (BN / 2) + j * 16 + cn;
            if (!GN || ncol < N) {
#pragma unroll
                for (int reg = 0; reg < 4; reg++)
                    C[(size_t)(trow + reg) * N + ncol] = acc[i][j][reg];
            }
        }
    }
}

// ------------- causal depthwise conv (k=4) + bias + SiLU, float4 -------------
__global__ void conv_silu_kernel(const float* __restrict__ xz,
                                 const float* __restrict__ cW,
                                 const float* __restrict__ cb,
                                 float* __restrict__ xc) {
    int idx = blockIdx.x * blockDim.x + threadIdx.x;  // 4-channel groups
    int d4 = (idx & 127) * 4;
    int t = idx >> 7;
    int l = t % SEQ;
    float4 acc = *(const float4*)(cb + d4);
    float4 wA = *(const float4*)(cW + (d4 + 0) * 4);
    float4 wB = *(const float4*)(cW + (d4 + 1) * 4);
    float4 wC = *(const float4*)(cW + (d4 + 2) * 4);
    float4 wD = *(const float4*)(cW + (d4 + 3) * 4);
#pragma unroll
    for (int k = 0; k < D_CONV; k++) {
        int ll = l - 3 + k;
        if (ll >= 0) {
            float4 v = *(const float4*)(xz + (size_t)(t - 3 + k) * 1024 + d4);
            float wa = (k == 0) ? wA.x : (k == 1) ? wA.y : (k == 2) ? wA.z : wA.w;
            float wb = (k == 0) ? wB.x : (k == 1) ? wB.y : (k == 2) ? wB.z : wB.w;
            float wc = (k == 0) ? wC.x : (k == 1) ? wC.y : (k == 2) ? wC.z : wC.w;
            float wd = (k == 0) ? wD.x : (k == 1) ? wD.y : (k == 2) ? wD.z : wD.w;
            acc.x = fmaf(v.x, wa, acc.x);
            acc.y = fmaf(v.y, wb, acc.y);
            acc.z = fmaf(v.z, wc, acc.z);
            acc.w = fmaf(v.w, wd, acc.w);
        }
    }
    float4 o;
    o.x = acc.x * fast_sig(acc.x);
    o.y = acc.y * fast_sig(acc.y);
    o.z = acc.z * fast_sig(acc.z);
    o.w = acc.w * fast_sig(acc.w);
    *(float4*)(xc + (size_t)t * 512 + d4) = o;
}

// ========== block-local 3-phase scan; 64 ch/wave; combine in LDS ==========
// grid (8,32) = (dg, b); block 768 thr = 12 waves; wave w = segment w.
// seg forced wave-uniform via readfirstlane so row addresses take the scalar
// (SGPR/s_load) path — rounds 3-8 pattern, no VGPR spills.
__global__ __launch_bounds__(768) void scan_block(
    float* xcio, const float* __restrict__ dbl, const float* __restrict__ xz,
    const float* __restrict__ A_log, const float* __restrict__ Dskip,
    const float* __restrict__ dtW, const float* __restrict__ dtb) {
    __shared__ float lh[NSEG * D_STATE * 64];   // [seg][s][ch]
    __shared__ float lsd[NSEG * 64];            // [seg][ch]
    const int dg = blockIdx.x, b = blockIdx.y;
    const int tid = threadIdx.x;
    const int lane = tid & 63;
    const int seg = __builtin_amdgcn_readfirstlane(tid >> 6);  // wave-uniform!
    const int d = (dg << 6) + lane;
    const float LOG2E = 1.44269504088896340736f;
    float ArowL2[D_STATE], dWr[DT_RANK];
#pragma unroll
    for (int s4 = 0; s4 < 4; s4++) {
        float4 v = *(const float4*)(A_log + (size_t)d * D_STATE + s4 * 4);
        ArowL2[s4 * 4 + 0] = -__expf(v.x) * LOG2E;
        ArowL2[s4 * 4 + 1] = -__expf(v.y) * LOG2E;
        ArowL2[s4 * 4 + 2] = -__expf(v.z) * LOG2E;
        ArowL2[s4 * 4 + 3] = -__expf(v.w) * LOG2E;
        float4 w = *(const float4*)(dtW + (size_t)d * DT_RANK + s4 * 4);
        dWr[s4 * 4 + 0] = w.x; dWr[s4 * 4 + 1] = w.y;
        dWr[s4 * 4 + 2] = w.z; dWr[s4 * 4 + 3] = w.w;
    }
    const float dtbv = dtb[d], dsk = Dskip[d];
    const size_t tb = (size_t)b * SEQ + (size_t)seg * SEGLEN;
    const float* __restrict__ dr = dbl + tb * 48;
    const float* xp = xcio + tb * 512 + d;
    const float* __restrict__ zp = xz + tb * 1024 + 512 + d;
    float* yp = xcio + tb * 512 + d;

    // ---------------- phase 1: local scan from h=0 ----------------
    {
        float h[D_STATE];
#pragma unroll
        for (int s = 0; s < D_STATE; s++) h[s] = 0.f;
        float sdt = 0.f;
        float dbA[32], dbB[32];
#pragma unroll
        for (int i = 0; i < 8; i++) ((float4*)dbA)[i] = ((const float4*)dr)[i];
        float xv = xp[0];
        for (int l = 0; l < SEGLEN; l += 2) {
            const float4* nr1 = (const float4*)(dr + (size_t)(l + 1) * 48);
#pragma unroll
            for (int i = 0; i < 8; i++) ((float4*)dbB)[i] = nr1[i];
            float xv1 = xp[(size_t)(l + 1) * 512];
            {
                float a0 = dtbv, a1 = 0.f, a2 = 0.f, a3 = 0.f;
#pragma unroll
                for (int r = 0; r < 4; r++) {
                    a0 = fmaf(dbA[r], dWr[r], a0);
                    a1 = fmaf(dbA[4 + r], dWr[4 + r], a1);
                    a2 = fmaf(dbA[8 + r], dWr[8 + r], a2);
                    a3 = fmaf(dbA[12 + r], dWr[12 + r], a3);
                }
                float acc = (a0 + a1) + (a2 + a3);
                float dtt = fmaxf(acc, 0.f) + __logf(1.f + __expf(-fabsf(acc)));
                sdt += dtt;
                float dtx = dtt * xv;
#pragma unroll
                for (int s = 0; s < D_STATE; s++) {
                    float dA = exp2f(dtt * ArowL2[s]);
                    h[s] = fmaf(dA, h[s], dtx * dbA[16 + s]);
                }
            }
            const float4* nr2 = (const float4*)(dr + (size_t)(l + 2) * 48);
#pragma unroll
            for (int i = 0; i < 8; i++) ((float4*)dbA)[i] = nr2[i];
            float xv2 = xp[(size_t)(l + 2) * 512];
            if (l + 1 < SEGLEN) {
                float a0 = dtbv, a1 = 0.f, a2 = 0.f, a3 = 0.f;
#pragma unroll
                for (int r = 0; r < 4; r++) {
                    a0 = fmaf(dbB[r], dWr[r], a0);
                    a1 = fmaf(dbB[4 + r], dWr[4 + r], a1);
                    a2 = fmaf(dbB[8 + r], dWr[8 + r], a2);
                    a3 = fmaf(dbB[12 + r], dWr[12 + r], a3);
                }
                float acc = (a0 + a1) + (a2 + a3);
                float dtt = fmaxf(acc, 0.f) + __logf(1.f + __expf(-fabsf(acc)));
                sdt += dtt;
                float dtx = dtt * xv1;
#pragma unroll
                for (int s = 0; s < D_STATE; s++) {
                    float dA = exp2f(dtt * ArowL2[s]);
                    h[s] = fmaf(dA, h[s], dtx * dbB[16 + s]);
                }
            }
            xv = xv2;
        }
#pragma unroll
        for (int s = 0; s < D_STATE; s++) lh[(seg * D_STATE + s) * 64 + lane] = h[s];
        lsd[seg * 64 + lane] = sdt;
    }
    __syncthreads();
    // ---------------- phase 2: in-LDS prefix combine ----------------
    for (int it = tid; it < D_STATE * 64; it += 768) {
        int ch = it & 63, s = it >> 6;
        float As2 = -__expf(A_log[(size_t)((dg << 6) + ch) * D_STATE + s]) * LOG2E;
        float H = 0.f;
        for (int sg = 0; sg < NSEG; sg++) {
            float hl = lh[(sg * D_STATE + s) * 64 + ch];
            float sd = lsd[sg * 64 + ch];
            lh[(sg * D_STATE + s) * 64 + ch] = H;
            H = fmaf(exp2f(As2 * sd), H, hl);
        }
    }
    __syncthreads();
    // ---------------- phase 3: re-scan from initial state ----------------
    {
        float h[D_STATE];
#pragma unroll
        for (int s = 0; s < D_STATE; s++) h[s] = lh[(seg * D_STATE + s) * 64 + lane];
        float dbA[48], dbB[48];
#pragma unroll
        for (int i = 0; i < 12; i++) ((float4*)dbA)[i] = ((const float4*)dr)[i];
        float xv = xp[0], zv = zp[0];
        for (int l = 0; l < SEGLEN; l += 2) {
            const float4* nr1 = (const float4*)(dr + (size_t)(l + 1) * 48);
#pragma unroll
            for (int i = 0; i < 12; i++) ((float4*)dbB)[i] = nr1[i];
            float xv1 = xp[(size_t)(l + 1) * 512];
            float zv1 = zp[(size_t)(l + 1) * 1024];
            {
                float a0 = dtbv, a1 = 0.f, a2 = 0.f, a3 = 0.f;
#pragma unroll
                for (int r = 0; r < 4; r++) {
                    a0 = fmaf(dbA[r], dWr[r], a0);
                    a1 = fmaf(dbA[4 + r], dWr[4 + r], a1);
                    a2 = fmaf(dbA[8 + r], dWr[8 + r], a2);
                    a3 = fmaf(dbA[12 + r], dWr[12 + r], a3);
                }
                float acc = (a0 + a1) + (a2 + a3);
                float dtt = fmaxf(acc, 0.f) + __logf(1.f + __expf(-fabsf(acc)));
                float dtx = dtt * xv;
                float y0 = 0.f, y1 = 0.f, y2 = 0.f, y3 = 0.f;
#pragma unroll
                for (int s = 0; s < 4; s++) {
                    float dA0 = exp2f(dtt * ArowL2[s]);
                    float dA1 = exp2f(dtt * ArowL2[4 + s]);
                    float dA2 = exp2f(dtt * ArowL2[8 + s]);
                    float dA3 = exp2f(dtt * ArowL2[12 + s]);
                    h[s] = fmaf(dA0, h[s], dtx * dbA[16 + s]);
                    h[4 + s] = fmaf(dA1, h[4 + s], dtx * dbA[20 + s]);
                    h[8 + s] = fmaf(dA2, h[8 + s], dtx * dbA[24 + s]);
                    h[12 + s] = fmaf(dA3, h[12 + s], dtx * dbA[28 + s]);
                    y0 = fmaf(h[s], dbA[32 + s], y0);
                    y1 = fmaf(h[4 + s], dbA[36 + s], y1);
                    y2 = fmaf(h[8 + s], dbA[40 + s], y2);
                    y3 = fmaf(h[12 + s], dbA[44 + s], y3);
                }
                float y = (y0 + y1) + (y2 + y3);
                yp[(size_t)l * 512] = (y + xv * dsk) * (zv * fast_sig(zv));
            }
            const float4* nr2 = (const float4*)(dr + (size_t)(l + 2) * 48);
#pragma unroll
            for (int i = 0; i < 12; i++) ((float4*)dbA)[i] = nr2[i];
            float xv2 = xp[(size_t)(l + 2) * 512];
            float zv2 = zp[(size_t)(l + 2) * 1024];
            if (l + 1 < SEGLEN) {
                float a0 = dtbv, a1 = 0.f, a2 = 0.f, a3 = 0.f;
#pragma unroll
                for (int r = 0; r < 4; r++) {
                    a0 = fmaf(dbB[r], dWr[r], a0);
                    a1 = fmaf(dbB[4 + r], dWr[4 + r], a1);
                    a2 = fmaf(dbB[8 + r], dWr[8 + r], a2);
                    a3 = fmaf(dbB[12 + r], dWr[12 + r], a3);
                }
                float acc = (a0 + a1) + (a2 + a3);
                float dtt = fmaxf(acc, 0.f) + __logf(1.f + __expf(-fabsf(acc)));
                float dtx = dtt * xv1;
                float y0 = 0.f, y1 = 0.f, y2 = 0.f, y3 = 0.f;
#pragma unroll
                for (int s = 0; s < 4; s++) {
                    float dA0 = exp2f(dtt * ArowL2[s]);
                    float dA1 = exp2f(dtt * ArowL2[4 + s]);
                    float dA2 = exp2f(dtt * ArowL2[8 + s]);
                    float dA3 = exp2f(dtt * ArowL2[12 + s]);
                    h[s] = fmaf(dA0, h[s], dtx * dbB[16 + s]);
                    h[4 + s] = fmaf(dA1, h[4 + s], dtx * dbB[20 + s]);
                    h[8 + s] = fmaf(dA2, h[8 + s], dtx * dbB[24 + s]);
                    h[12 + s] = fmaf(dA3, h[12 + s], dtx * dbB[28 + s]);
                    y0 = fmaf(h[s], dbB[32 + s], y0);
                    y1 = fmaf(h[4 + s], dbB[36 + s], y1);
                    y2 = fmaf(h[8 + s], dbB[40 + s], y2);
                    y3 = fmaf(h[12 + s], dbB[44 + s], y3);
                }
                float y = (y0 + y1) + (y2 + y3);
                yp[(size_t)(l + 1) * 512] = (y + xv1 * dsk) * (zv1 * fast_sig(zv1));
            }
            xv = xv2; zv = zv2;
        }
    }
}

extern "C" void kernel_launch(void* const* d_in, const int* in_sizes, int n_in,
                              void* d_out, int out_size, void* d_ws, size_t ws_size,
                              hipStream_t stream) {
    const float* coords   = (const float*)d_in[0];
    const float* emb_W    = (const float*)d_in[1];
    const float* emb_b    = (const float*)d_in[2];
    const float* ln_w     = (const float*)d_in[3];
    const float* ln_b     = (const float*)d_in[4];
    const float* in_W     = (const float*)d_in[5];
    const float* conv_W   = (const float*)d_in[6];
    const float* conv_b   = (const float*)d_in[7];
    const float* xproj_W  = (const float*)d_in[8];
    const float* dtproj_W = (const float*)d_in[9];
    const float* dtproj_b = (const float*)d_in[10];
    const float* A_log    = (const float*)d_in[11];
    const float* D_skip   = (const float*)d_in[12];
    const float* out_W    = (const float*)d_in[13];
    const float* normf_w  = (const float*)d_in[14];
    const float* normf_b  = (const float*)d_in[15];
    const float* head_W   = (const float*)d_in[16];
    float* out = (float*)d_out;

    const int T = NTOK;  // 9600
    float* x     = (float*)d_ws;
    float* resid = x + (size_t)T * D_MODEL;
    float* h     = resid + (size_t)T * D_MODEL;
    float* xz    = h + (size_t)T * D_MODEL;
    float* xc    = xz + (size_t)T * 2 * D_INNER;   // conv output, then scan output (in place)
    float* dbl   = xc + (size_t)T * D_INNER;

    embed_kernel<<<T, D_MODEL, 0, stream>>>(coords, emb_W, emb_b, x);

    for (int i = 0; i < N_LAYERS; i++) {
        ln_res_kernel<<<T, D_MODEL, 0, stream>>>(x, resid, h, ln_w + i * D_MODEL,
                                                 ln_b + i * D_MODEL, i == 0);
        // in_proj: (9600,256) x (1024,256)^T -> (9600,1024)
        gemm_mfma<128, 128, false><<<dim3(T / 128, 8), 256, 0, stream>>>(
            h, in_W + (size_t)i * 2 * D_INNER * D_MODEL, xz, 2 * D_INNER, D_MODEL);
        conv_silu_kernel<<<T * 128 / 256, 256, 0, stream>>>(
            xz, conv_W + i * D_INNER * D_CONV, conv_b + i * D_INNER, xc);
        // xproj: (9600,512) x (48,512)^T -> (9600,48)
        gemm_mfma<64, 64, true><<<dim3(T / 64, 1), 256, 0, stream>>>(
            xc, xproj_W + (size_t)i * 48 * D_INNER, dbl, 48, D_INNER);
        // block-local 3-phase scan (seg wave-uniform -> scalar row loads)
        scan_block<<<dim3(8, BATCH), 768, 0, stream>>>(
            xc, dbl, xz, A_log + (size_t)i * D_INNER * D_STATE, D_skip + i * D_INNER,
            dtproj_W + (size_t)i * D_INNER * DT_RANK, dtproj_b + i * D_INNER);
        // out_proj: (9600,512) x (256,512)^T -> (9600,256)
        gemm_mfma<64, 64, false><<<dim3(T / 64, 4), 256, 0, stream>>>(
            xc, out_W + (size_t)i * D_MODEL * D_INNER, x, D_MODEL, D_INNER);
    }

    final_rms_kernel<<<T, D_MODEL, 0, stream>>>(x, resid, normf_w, normf_b, h);
    // head: (9600,256) x (300,256)^T -> (9600,300)
    gemm_mfma<64, 64, true><<<dim3(T / 64, 5), 256, 0, stream>>>(
        h, head_W, out, CITY, D_MODEL);
}